// Round 12
// baseline (612.816 us; speedup 1.0000x reference)
//
#include <hip/hip_runtime.h>

#define NUM_BINS 15
#define N_CTX 32
#define C_IMG 3
#define HGT 512
#define WID 512
#define HW (HGT * WID)

#define SEG 4                        // emitted rows per wave-unit
#define NSEG (HGT / SEG)             // 128
#define UNITS (N_CTX * NSEG)         // 4096 waves = 4/SIMD, 1024 blocks = 4/CU

// ---------------------------------------------------------------------------
// Kernel 0: sumLab = sum_n labs[n]; zero the global histogram. float4 loads.
// ---------------------------------------------------------------------------
__global__ __launch_bounds__(256) void k_sumlab(const float4* __restrict__ labs,
                                                float4* __restrict__ sumLab,
                                                unsigned int* __restrict__ hist) {
    int i = blockIdx.x * 256 + threadIdx.x;
    if (blockIdx.x == 0 && threadIdx.x < 2 * NUM_BINS) hist[threadIdx.x] = 0u;
    float4 s = make_float4(0.f, 0.f, 0.f, 0.f);
    #pragma unroll
    for (int n = 0; n < N_CTX; ++n) {
        float4 v = labs[(size_t)n * (HW / 4) + i];
        s.x += v.x; s.y += v.y; s.z += v.z; s.w += v.w;
    }
    sumLab[i] = s;
}

// ---------------------------------------------------------------------------
// Per-unit streaming body. EDGE=true only for seg 0 and NSEG-1 (adds row
// clamps/masks); EDGE=false multiplies by literal 1.0f which folds away.
// Loads for row r+1 are issued into C AFTER all reads of row r (WAR order),
// so the load->use gap is the sigmoid/pool/emit tail of the iteration.
// ---------------------------------------------------------------------------
template<bool EDGE>
__device__ __forceinline__ void unit_body(const float* __restrict__ pi0,
                                          const float* __restrict__ pi1,
                                          const float* __restrict__ pi2,
                                          const float* __restrict__ pla,
                                          const float* __restrict__ psu,
                                          int y0, int lane,
                                          const float (&w)[4][3][3],
                                          unsigned int (&accC)[4],
                                          unsigned int (&accP)[4]) {
    const bool l0  = (lane == 0);
    const bool l63 = (lane == 63);
    const float inv31 = 1.0f / 31.0f;

    float hA2[8], hA1[8], hB1[8], hs2[8], hs1[8];
    #pragma unroll
    for (int c = 0; c < 8; ++c) { hA2[c] = hA1[c] = hB1[c] = 0.f; hs2[c] = hs1[c] = 0.f; }
    unsigned int pm1 = 0u, pm2 = 0u;   // label>0.5 bitmask ring (8 cols/lane)

    float4 C[10];
    auto loadC = [&](int rr) {
        int rc = rr;
        if (EDGE) rc = rr < 0 ? 0 : (rr > HGT - 1 ? HGT - 1 : rr);
        const size_t ro = (size_t)rc * WID;
        C[0] = *reinterpret_cast<const float4*>(pi0 + ro);
        C[1] = *reinterpret_cast<const float4*>(pi0 + ro + 4);
        C[2] = *reinterpret_cast<const float4*>(pi1 + ro);
        C[3] = *reinterpret_cast<const float4*>(pi1 + ro + 4);
        C[4] = *reinterpret_cast<const float4*>(pi2 + ro);
        C[5] = *reinterpret_cast<const float4*>(pi2 + ro + 4);
        C[6] = *reinterpret_cast<const float4*>(pla + ro);
        C[7] = *reinterpret_cast<const float4*>(pla + ro + 4);
        C[8] = *reinterpret_cast<const float4*>(psu + ro);
        C[9] = *reinterpret_cast<const float4*>(psu + ro + 4);
    };

    loadC(y0 - 2);
    float mcur = 1.f;
    if (EDGE) mcur = (y0 - 2 >= 0 && y0 - 2 < HGT) ? 1.f : 0.f;

    #pragma unroll 2
    for (int it = 0; it < SEG + 4; ++it) {
        const int r = y0 - 2 + it;
        const float mm  = EDGE ? mcur : 1.0f;           // folds to 1 in fast path
        const float i31 = EDGE ? inv31 * mcur : inv31;

        // label bitmask for this row (masked off out-of-image rows)
        unsigned int pm0 = (C[6].x > 0.5f ? 1u : 0u)  | (C[6].y > 0.5f ? 2u : 0u)
                         | (C[6].z > 0.5f ? 4u : 0u)  | (C[6].w > 0.5f ? 8u : 0u)
                         | (C[7].x > 0.5f ? 16u : 0u) | (C[7].y > 0.5f ? 32u : 0u)
                         | (C[7].z > 0.5f ? 64u : 0u) | (C[7].w > 0.5f ? 128u : 0u);
        if (EDGE) pm0 = (mcur == 0.f) ? 0u : pm0;

        // value vectors: left halo, 8 own, right halo (mm folds away when 1)
        float v[4][10];
        v[0][1] = C[0].x * mm; v[0][2] = C[0].y * mm; v[0][3] = C[0].z * mm; v[0][4] = C[0].w * mm;
        v[0][5] = C[1].x * mm; v[0][6] = C[1].y * mm; v[0][7] = C[1].z * mm; v[0][8] = C[1].w * mm;
        v[1][1] = C[2].x * mm; v[1][2] = C[2].y * mm; v[1][3] = C[2].z * mm; v[1][4] = C[2].w * mm;
        v[1][5] = C[3].x * mm; v[1][6] = C[3].y * mm; v[1][7] = C[3].z * mm; v[1][8] = C[3].w * mm;
        v[2][1] = C[4].x * mm; v[2][2] = C[4].y * mm; v[2][3] = C[4].z * mm; v[2][4] = C[4].w * mm;
        v[2][5] = C[5].x * mm; v[2][6] = C[5].y * mm; v[2][7] = C[5].z * mm; v[2][8] = C[5].w * mm;
        v[3][1] = (C[8].x - C[6].x) * i31;
        v[3][2] = (C[8].y - C[6].y) * i31;
        v[3][3] = (C[8].z - C[6].z) * i31;
        v[3][4] = (C[8].w - C[6].w) * i31;
        v[3][5] = (C[9].x - C[7].x) * i31;
        v[3][6] = (C[9].y - C[7].y) * i31;
        v[3][7] = (C[9].z - C[7].z) * i31;
        v[3][8] = (C[9].w - C[7].w) * i31;
        #pragma unroll
        for (int p = 0; p < 4; ++p) {
            float lft = __shfl_up(v[p][8], 1);
            float rgt = __shfl_down(v[p][1], 1);
            v[p][0] = l0  ? 0.f : lft;
            v[p][9] = l63 ? 0.f : rgt;
        }

        // horizontal 3-tap per kernel-row, accumulated over planes
        float h0[8], h1[8], h2[8];
        #pragma unroll
        for (int c = 0; c < 8; ++c) { h0[c] = 0.f; h1[c] = 0.f; h2[c] = 0.f; }
        #pragma unroll
        for (int p = 0; p < 4; ++p)
            #pragma unroll
            for (int c = 0; c < 8; ++c) {
                h0[c] += w[p][0][0] * v[p][c] + w[p][0][1] * v[p][c + 1] + w[p][0][2] * v[p][c + 2];
                h1[c] += w[p][1][0] * v[p][c] + w[p][1][1] * v[p][c + 1] + w[p][1][2] * v[p][c + 2];
                h2[c] += w[p][2][0] * v[p][c] + w[p][2][1] * v[p][c + 1] + w[p][2][2] * v[p][c + 2];
            }

        // ---- issue next-row loads into C (all reads of C are done above) ----
        if (it < SEG + 3) loadC(r + 1);
        if (EDGE) mcur = (r + 1 >= 0 && r + 1 < HGT) ? 1.f : 0.f;

        // z(y=r-1) = h0(r-2) + h1(r-1) + h2(r); sigmoid via 1-instr rcp
        const bool yv = EDGE ? (r - 1 >= 0 && r - 1 < HGT) : true;
        float pc_[8];
        #pragma unroll
        for (int c = 0; c < 8; ++c) {
            float z = hA2[c] + hB1[c] + h2[c];
            float pr = __builtin_amdgcn_rcpf(1.0f + __expf(-z));
            pc_[c] = yv ? pr : 0.f;
        }
        #pragma unroll
        for (int c = 0; c < 8; ++c) { hA2[c] = hA1[c]; hA1[c] = h0[c]; hB1[c] = h1[c]; }

        // horizontal pool sums
        float hsv[8];
        {
            float lft = __shfl_up(pc_[7], 1);
            float rgt = __shfl_down(pc_[0], 1);
            float pl_ = l0  ? 0.f : lft;
            float pr_ = l63 ? 0.f : rgt;
            hsv[0] = pl_ + pc_[0] + pc_[1];
            #pragma unroll
            for (int c = 1; c < 7; ++c) hsv[c] = pc_[c - 1] + pc_[c] + pc_[c + 1];
            hsv[7] = pc_[6] + pc_[7] + pr_;
        }

        // emit pooled row yc = r-2
        if (it >= 4) {
            float cbi, cbe;
            if (EDGE) {
                const int yc = r - 2;
                const bool row3 = (yc != 0) & (yc != HGT - 1);
                cbi = row3 ? (15.0f / 9.0f) : 2.5f;
                cbe = row3 ? 2.5f : 3.75f;
            } else {
                cbi = 15.0f / 9.0f;
                cbe = 2.5f;
            }
            const float cb0 = l0  ? cbe : cbi;
            const float cb7 = l63 ? cbe : cbi;
            const unsigned int posm = pm2;
            #pragma unroll
            for (int c = 0; c < 8; ++c) {
                const float psum = hs2[c] + hs1[c] + hsv[c];
                const float cb = (c == 0) ? cb0 : ((c == 7) ? cb7 : cbi);
                int b = (int)(psum * cb);
                b = b > NUM_BINS - 1 ? NUM_BINS - 1 : b;
                const unsigned int inc = 1u << ((b & 3) << 3);
                const int rs = b >> 2;
                const unsigned int incp = ((posm >> c) & 1u) ? inc : 0u;
                #pragma unroll
                for (int k = 0; k < 4; ++k) {
                    const bool mk = (rs == k);
                    accC[k] += mk ? inc : 0u;
                    accP[k] += mk ? incp : 0u;
                }
            }
        }

        // ring updates
        #pragma unroll
        for (int c = 0; c < 8; ++c) { hs2[c] = hs1[c]; hs1[c] = hsv[c]; }
        pm2 = pm1; pm1 = pm0;
    }
}

// ---------------------------------------------------------------------------
// Kernel 1: streaming conv -> sigmoid -> 3x3 valid-count pool -> histogram.
// One wave per (n, seg); each lane owns 8 contiguous columns (full 512 row).
// 1024 blocks = 4/CU, 4 waves/SIMD.
// ---------------------------------------------------------------------------
__global__ __launch_bounds__(256, 4) void k_main(const float* __restrict__ imgs,
                                                 const float* __restrict__ labs,
                                                 const float* __restrict__ sumLab,
                                                 const float* __restrict__ w_img,
                                                 const float* __restrict__ w_lab,
                                                 unsigned int* __restrict__ hist) {
    __shared__ unsigned int sh[2 * NUM_BINS];
    const int tid  = threadIdx.x;
    const int lane = tid & 63;
    const int u    = blockIdx.x * 4 + (tid >> 6);
    const int n    = u >> 7;             // u / NSEG
    const int seg  = u & (NSEG - 1);     // u % NSEG
    const int y0   = seg * SEG;
    const int x0   = lane * 8;

    if (tid < 2 * NUM_BINS) sh[tid] = 0u;
    __syncthreads();

    // 3x3 weights, 4 planes (img0..2, loo) — uniform
    float w[4][3][3];
    #pragma unroll
    for (int c = 0; c < 3; ++c)
        #pragma unroll
        for (int i = 0; i < 3; ++i)
            #pragma unroll
            for (int j = 0; j < 3; ++j)
                w[c][i][j] = w_img[c * 9 + i * 3 + j];
    #pragma unroll
    for (int i = 0; i < 3; ++i)
        #pragma unroll
        for (int j = 0; j < 3; ++j)
            w[3][i][j] = w_lab[i * 3 + j];

    const float* pi0 = imgs + (size_t)n * C_IMG * HW + x0;
    const float* pi1 = pi0 + HW;
    const float* pi2 = pi0 + 2 * HW;
    const float* pla = labs + (size_t)n * HW + x0;
    const float* psu = sumLab + x0;

    unsigned int accC[4] = {0u, 0u, 0u, 0u};
    unsigned int accP[4] = {0u, 0u, 0u, 0u};

    if (seg == 0 || seg == NSEG - 1)
        unit_body<true>(pi0, pi1, pi2, pla, psu, y0, lane, w, accC, accP);
    else
        unit_body<false>(pi0, pi1, pi2, pla, psu, y0, lane, w, accC, accP);

    // flush: unpack bytes, wave-reduce, one LDS atomic set per wave
    #pragma unroll
    for (int b = 0; b < NUM_BINS; ++b) {
        unsigned int c = (accC[b >> 2] >> ((b & 3) * 8)) & 0xffu;
        unsigned int p = (accP[b >> 2] >> ((b & 3) * 8)) & 0xffu;
        #pragma unroll
        for (int off = 1; off < 64; off <<= 1) {
            c += __shfl_xor(c, off);
            p += __shfl_xor(p, off);
        }
        if (lane == 0) {
            atomicAdd(&sh[b], c);
            atomicAdd(&sh[NUM_BINS + b], p);
        }
    }
    __syncthreads();
    if (tid < 2 * NUM_BINS) {
        unsigned int vsum = sh[tid];
        if (vsum) atomicAdd(&hist[tid], vsum);
    }
}

// ---------------------------------------------------------------------------
// Kernel 2: bin_freqs + gather for target pixels (bit-exact path).
// ---------------------------------------------------------------------------
__global__ __launch_bounds__(256) void k_out(const float4* __restrict__ tl,
                                             const unsigned int* __restrict__ hist,
                                             float4* __restrict__ out) {
    __shared__ float s_f[NUM_BINS];
    const float BIN_W = (float)(1.0 / 15.0);
    int tid = threadIdx.x;
    if (tid < NUM_BINS) {
        unsigned int c = hist[tid];
        unsigned int p = hist[NUM_BINS + tid];
        s_f[tid] = (c > 0u) ? (float)p / (float)c : 0.0f;
    }
    __syncthreads();
    int i = blockIdx.x * 256 + tid;
    float4 t = tl[i];
    float4 o;
    {
        float pr = 1.0f / (1.0f + expf(-t.x));
        int b = (int)(pr / BIN_W); b = b < 0 ? 0 : (b > NUM_BINS - 1 ? NUM_BINS - 1 : b);
        o.x = s_f[b];
    }
    {
        float pr = 1.0f / (1.0f + expf(-t.y));
        int b = (int)(pr / BIN_W); b = b < 0 ? 0 : (b > NUM_BINS - 1 ? NUM_BINS - 1 : b);
        o.y = s_f[b];
    }
    {
        float pr = 1.0f / (1.0f + expf(-t.z));
        int b = (int)(pr / BIN_W); b = b < 0 ? 0 : (b > NUM_BINS - 1 ? NUM_BINS - 1 : b);
        o.z = s_f[b];
    }
    {
        float pr = 1.0f / (1.0f + expf(-t.w));
        int b = (int)(pr / BIN_W); b = b < 0 ? 0 : (b > NUM_BINS - 1 ? NUM_BINS - 1 : b);
        o.w = s_f[b];
    }
    out[i] = o;
}

extern "C" void kernel_launch(void* const* d_in, const int* in_sizes, int n_in,
                              void* d_out, int out_size, void* d_ws, size_t ws_size,
                              hipStream_t stream) {
    const float* imgs  = (const float*)d_in[0];  // [1,32,3,512,512]
    const float* labs  = (const float*)d_in[1];  // [1,32,1,512,512]
    const float* tlog  = (const float*)d_in[2];  // [1,1,512,512]
    const float* w_img = (const float*)d_in[3];  // [1,3,3,3]
    const float* w_lab = (const float*)d_in[4];  // [1,1,3,3]
    float* out = (float*)d_out;

    float* sumLab = (float*)d_ws;                                       // HW floats
    unsigned int* hist = (unsigned int*)((char*)d_ws + (size_t)HW * sizeof(float));

    k_sumlab<<<HW / 4 / 256, 256, 0, stream>>>((const float4*)labs, (float4*)sumLab, hist);

    k_main<<<UNITS / 4, 256, 0, stream>>>(imgs, labs, sumLab, w_img, w_lab, hist);

    k_out<<<HW / 4 / 256, 256, 0, stream>>>((const float4*)tlog, hist, (float4*)out);
}

// Round 14
// 221.842 us; speedup vs baseline: 2.7624x; 2.7624x over previous
//
#include <hip/hip_runtime.h>

#define NUM_BINS 15
#define N_CTX 32
#define C_IMG 3
#define HGT 512
#define WID 512
#define HW (HGT * WID)

#define SEG 4                        // emitted rows per wave-unit
#define NSEG (HGT / SEG)             // 128
#define UNITS (N_CTX * NSEG)         // 4096 waves, 1024 blocks = 4/CU

// ---------------------------------------------------------------------------
// Kernel 0: sumLab = sum_n labs[n]; zero the global histogram. float4 loads.
// ---------------------------------------------------------------------------
__global__ __launch_bounds__(256) void k_sumlab(const float4* __restrict__ labs,
                                                float4* __restrict__ sumLab,
                                                unsigned int* __restrict__ hist) {
    int i = blockIdx.x * 256 + threadIdx.x;
    if (blockIdx.x == 0 && threadIdx.x < 2 * NUM_BINS) hist[threadIdx.x] = 0u;
    float4 s = make_float4(0.f, 0.f, 0.f, 0.f);
    #pragma unroll
    for (int n = 0; n < N_CTX; ++n) {
        float4 v = labs[(size_t)n * (HW / 4) + i];
        s.x += v.x; s.y += v.y; s.z += v.z; s.w += v.w;
    }
    sumLab[i] = s;
}

// load row rr into named registers (clamped only in EDGE instantiation)
#define LOAD_ROW(rr)                                                         \
    {                                                                        \
        int rc_ = (rr);                                                      \
        if (EDGE) rc_ = rc_ < 0 ? 0 : (rc_ > HGT - 1 ? HGT - 1 : rc_);       \
        const size_t ro_ = (size_t)rc_ * WID;                                \
        c0 = *reinterpret_cast<const float4*>(pi0 + ro_);                    \
        c1 = *reinterpret_cast<const float4*>(pi0 + ro_ + 4);                \
        c2 = *reinterpret_cast<const float4*>(pi1 + ro_);                    \
        c3 = *reinterpret_cast<const float4*>(pi1 + ro_ + 4);                \
        c4 = *reinterpret_cast<const float4*>(pi2 + ro_);                    \
        c5 = *reinterpret_cast<const float4*>(pi2 + ro_ + 4);                \
        c6 = *reinterpret_cast<const float4*>(pla + ro_);                    \
        c7 = *reinterpret_cast<const float4*>(pla + ro_ + 4);                \
        c8 = *reinterpret_cast<const float4*>(psu + ro_);                    \
        c9 = *reinterpret_cast<const float4*>(psu + ro_ + 4);                \
    }

// ---------------------------------------------------------------------------
// Per-unit streaming body. EDGE=true only for seg 0 and NSEG-1.
// Row r+1 loads are issued into c0..c9 AFTER all reads of row r (WAR order);
// fully-unrolled loop keeps every register access statically named.
// ---------------------------------------------------------------------------
template<bool EDGE>
__device__ __forceinline__ void unit_body(const float* __restrict__ pi0,
                                          const float* __restrict__ pi1,
                                          const float* __restrict__ pi2,
                                          const float* __restrict__ pla,
                                          const float* __restrict__ psu,
                                          int y0, int lane,
                                          const float (&w)[4][3][3],
                                          unsigned int (&accC)[4],
                                          unsigned int (&accP)[4]) {
    const bool l0  = (lane == 0);
    const bool l63 = (lane == 63);
    const float inv31 = 1.0f / 31.0f;

    float hA2[8], hA1[8], hB1[8], hs2[8], hs1[8];
    #pragma unroll
    for (int c = 0; c < 8; ++c) { hA2[c] = hA1[c] = hB1[c] = 0.f; hs2[c] = hs1[c] = 0.f; }
    unsigned int pm1 = 0u, pm2 = 0u;   // label>0.5 bitmask ring (8 cols/lane)

    float4 c0, c1, c2, c3, c4, c5, c6, c7, c8, c9;
    LOAD_ROW(y0 - 2);
    float mcur = 1.f;
    if (EDGE) mcur = (y0 - 2 >= 0 && y0 - 2 < HGT) ? 1.f : 0.f;

    #pragma unroll
    for (int it = 0; it < SEG + 4; ++it) {
        const int r = y0 - 2 + it;
        const float mm  = EDGE ? mcur : 1.0f;           // folds to 1 in fast path
        const float i31 = EDGE ? inv31 * mcur : inv31;

        // label bitmask for this row (masked off out-of-image rows)
        unsigned int pm0 = (c6.x > 0.5f ? 1u : 0u)  | (c6.y > 0.5f ? 2u : 0u)
                         | (c6.z > 0.5f ? 4u : 0u)  | (c6.w > 0.5f ? 8u : 0u)
                         | (c7.x > 0.5f ? 16u : 0u) | (c7.y > 0.5f ? 32u : 0u)
                         | (c7.z > 0.5f ? 64u : 0u) | (c7.w > 0.5f ? 128u : 0u);
        if (EDGE) pm0 = (mcur == 0.f) ? 0u : pm0;

        // value vectors: left halo, 8 own, right halo (mm folds away when 1)
        float v[4][10];
        v[0][1] = c0.x * mm; v[0][2] = c0.y * mm; v[0][3] = c0.z * mm; v[0][4] = c0.w * mm;
        v[0][5] = c1.x * mm; v[0][6] = c1.y * mm; v[0][7] = c1.z * mm; v[0][8] = c1.w * mm;
        v[1][1] = c2.x * mm; v[1][2] = c2.y * mm; v[1][3] = c2.z * mm; v[1][4] = c2.w * mm;
        v[1][5] = c3.x * mm; v[1][6] = c3.y * mm; v[1][7] = c3.z * mm; v[1][8] = c3.w * mm;
        v[2][1] = c4.x * mm; v[2][2] = c4.y * mm; v[2][3] = c4.z * mm; v[2][4] = c4.w * mm;
        v[2][5] = c5.x * mm; v[2][6] = c5.y * mm; v[2][7] = c5.z * mm; v[2][8] = c5.w * mm;
        v[3][1] = (c8.x - c6.x) * i31;
        v[3][2] = (c8.y - c6.y) * i31;
        v[3][3] = (c8.z - c6.z) * i31;
        v[3][4] = (c8.w - c6.w) * i31;
        v[3][5] = (c9.x - c7.x) * i31;
        v[3][6] = (c9.y - c7.y) * i31;
        v[3][7] = (c9.z - c7.z) * i31;
        v[3][8] = (c9.w - c7.w) * i31;
        #pragma unroll
        for (int p = 0; p < 4; ++p) {
            float lft = __shfl_up(v[p][8], 1);
            float rgt = __shfl_down(v[p][1], 1);
            v[p][0] = l0  ? 0.f : lft;
            v[p][9] = l63 ? 0.f : rgt;
        }

        // horizontal 3-tap per kernel-row, accumulated over planes
        float h0[8], h1[8], h2[8];
        #pragma unroll
        for (int c = 0; c < 8; ++c) { h0[c] = 0.f; h1[c] = 0.f; h2[c] = 0.f; }
        #pragma unroll
        for (int p = 0; p < 4; ++p)
            #pragma unroll
            for (int c = 0; c < 8; ++c) {
                h0[c] += w[p][0][0] * v[p][c] + w[p][0][1] * v[p][c + 1] + w[p][0][2] * v[p][c + 2];
                h1[c] += w[p][1][0] * v[p][c] + w[p][1][1] * v[p][c + 1] + w[p][1][2] * v[p][c + 2];
                h2[c] += w[p][2][0] * v[p][c] + w[p][2][1] * v[p][c + 1] + w[p][2][2] * v[p][c + 2];
            }

        // ---- issue next-row loads (all reads of c0..c9 are done above) ----
        if (it < SEG + 3) LOAD_ROW(r + 1);
        if (EDGE) mcur = (r + 1 >= 0 && r + 1 < HGT) ? 1.f : 0.f;

        // z(y=r-1) = h0(r-2) + h1(r-1) + h2(r); sigmoid via 1-instr rcp
        const bool yv = EDGE ? (r - 1 >= 0 && r - 1 < HGT) : true;
        float pc_[8];
        #pragma unroll
        for (int c = 0; c < 8; ++c) {
            float z = hA2[c] + hB1[c] + h2[c];
            float pr = __builtin_amdgcn_rcpf(1.0f + __expf(-z));
            pc_[c] = yv ? pr : 0.f;
        }
        #pragma unroll
        for (int c = 0; c < 8; ++c) { hA2[c] = hA1[c]; hA1[c] = h0[c]; hB1[c] = h1[c]; }

        // horizontal pool sums
        float hsv[8];
        {
            float lft = __shfl_up(pc_[7], 1);
            float rgt = __shfl_down(pc_[0], 1);
            float pl_ = l0  ? 0.f : lft;
            float pr_ = l63 ? 0.f : rgt;
            hsv[0] = pl_ + pc_[0] + pc_[1];
            #pragma unroll
            for (int c = 1; c < 7; ++c) hsv[c] = pc_[c - 1] + pc_[c] + pc_[c + 1];
            hsv[7] = pc_[6] + pc_[7] + pr_;
        }

        // emit pooled row yc = r-2
        if (it >= 4) {
            float cbi, cbe;
            if (EDGE) {
                const int yc = r - 2;
                const bool row3 = (yc != 0) & (yc != HGT - 1);
                cbi = row3 ? (15.0f / 9.0f) : 2.5f;
                cbe = row3 ? 2.5f : 3.75f;
            } else {
                cbi = 15.0f / 9.0f;
                cbe = 2.5f;
            }
            const float cb0 = l0  ? cbe : cbi;
            const float cb7 = l63 ? cbe : cbi;
            const unsigned int posm = pm2;
            #pragma unroll
            for (int c = 0; c < 8; ++c) {
                const float psum = hs2[c] + hs1[c] + hsv[c];
                const float cb = (c == 0) ? cb0 : ((c == 7) ? cb7 : cbi);
                int b = (int)(psum * cb);
                b = b > NUM_BINS - 1 ? NUM_BINS - 1 : b;
                const unsigned int inc = 1u << ((b & 3) << 3);
                const int rs = b >> 2;
                const unsigned int incp = ((posm >> c) & 1u) ? inc : 0u;
                #pragma unroll
                for (int k = 0; k < 4; ++k) {
                    const bool mk = (rs == k);
                    accC[k] += mk ? inc : 0u;
                    accP[k] += mk ? incp : 0u;
                }
            }
        }

        // ring updates
        #pragma unroll
        for (int c = 0; c < 8; ++c) { hs2[c] = hs1[c]; hs1[c] = hsv[c]; }
        pm2 = pm1; pm1 = pm0;
    }
}

// ---------------------------------------------------------------------------
// Kernel 1: streaming conv -> sigmoid -> 3x3 valid-count pool -> histogram.
// One wave per (n, seg); each lane owns 8 contiguous columns (full 512 row).
// 1024 blocks; launch_bounds (256,2) = proven no-spill register budget.
// ---------------------------------------------------------------------------
__global__ __launch_bounds__(256, 2) void k_main(const float* __restrict__ imgs,
                                                 const float* __restrict__ labs,
                                                 const float* __restrict__ sumLab,
                                                 const float* __restrict__ w_img,
                                                 const float* __restrict__ w_lab,
                                                 unsigned int* __restrict__ hist) {
    __shared__ unsigned int sh[2 * NUM_BINS];
    const int tid  = threadIdx.x;
    const int lane = tid & 63;
    const int u    = blockIdx.x * 4 + (tid >> 6);
    const int n    = u >> 7;             // u / NSEG
    const int seg  = u & (NSEG - 1);     // u % NSEG
    const int y0   = seg * SEG;
    const int x0   = lane * 8;

    if (tid < 2 * NUM_BINS) sh[tid] = 0u;
    __syncthreads();

    // 3x3 weights, 4 planes (img0..2, loo) — uniform
    float w[4][3][3];
    #pragma unroll
    for (int c = 0; c < 3; ++c)
        #pragma unroll
        for (int i = 0; i < 3; ++i)
            #pragma unroll
            for (int j = 0; j < 3; ++j)
                w[c][i][j] = w_img[c * 9 + i * 3 + j];
    #pragma unroll
    for (int i = 0; i < 3; ++i)
        #pragma unroll
        for (int j = 0; j < 3; ++j)
            w[3][i][j] = w_lab[i * 3 + j];

    const float* pi0 = imgs + (size_t)n * C_IMG * HW + x0;
    const float* pi1 = pi0 + HW;
    const float* pi2 = pi0 + 2 * HW;
    const float* pla = labs + (size_t)n * HW + x0;
    const float* psu = sumLab + x0;

    unsigned int accC[4] = {0u, 0u, 0u, 0u};
    unsigned int accP[4] = {0u, 0u, 0u, 0u};

    if (seg == 0 || seg == NSEG - 1)
        unit_body<true>(pi0, pi1, pi2, pla, psu, y0, lane, w, accC, accP);
    else
        unit_body<false>(pi0, pi1, pi2, pla, psu, y0, lane, w, accC, accP);

    // flush: unpack bytes, wave-reduce, one LDS atomic set per wave
    #pragma unroll
    for (int b = 0; b < NUM_BINS; ++b) {
        unsigned int c = (accC[b >> 2] >> ((b & 3) * 8)) & 0xffu;
        unsigned int p = (accP[b >> 2] >> ((b & 3) * 8)) & 0xffu;
        #pragma unroll
        for (int off = 1; off < 64; off <<= 1) {
            c += __shfl_xor(c, off);
            p += __shfl_xor(p, off);
        }
        if (lane == 0) {
            atomicAdd(&sh[b], c);
            atomicAdd(&sh[NUM_BINS + b], p);
        }
    }
    __syncthreads();
    if (tid < 2 * NUM_BINS) {
        unsigned int vsum = sh[tid];
        if (vsum) atomicAdd(&hist[tid], vsum);
    }
}

// ---------------------------------------------------------------------------
// Kernel 2: bin_freqs + gather for target pixels (bit-exact path).
// ---------------------------------------------------------------------------
__global__ __launch_bounds__(256) void k_out(const float4* __restrict__ tl,
                                             const unsigned int* __restrict__ hist,
                                             float4* __restrict__ out) {
    __shared__ float s_f[NUM_BINS];
    const float BIN_W = (float)(1.0 / 15.0);
    int tid = threadIdx.x;
    if (tid < NUM_BINS) {
        unsigned int c = hist[tid];
        unsigned int p = hist[NUM_BINS + tid];
        s_f[tid] = (c > 0u) ? (float)p / (float)c : 0.0f;
    }
    __syncthreads();
    int i = blockIdx.x * 256 + tid;
    float4 t = tl[i];
    float4 o;
    {
        float pr = 1.0f / (1.0f + expf(-t.x));
        int b = (int)(pr / BIN_W); b = b < 0 ? 0 : (b > NUM_BINS - 1 ? NUM_BINS - 1 : b);
        o.x = s_f[b];
    }
    {
        float pr = 1.0f / (1.0f + expf(-t.y));
        int b = (int)(pr / BIN_W); b = b < 0 ? 0 : (b > NUM_BINS - 1 ? NUM_BINS - 1 : b);
        o.y = s_f[b];
    }
    {
        float pr = 1.0f / (1.0f + expf(-t.z));
        int b = (int)(pr / BIN_W); b = b < 0 ? 0 : (b > NUM_BINS - 1 ? NUM_BINS - 1 : b);
        o.z = s_f[b];
    }
    {
        float pr = 1.0f / (1.0f + expf(-t.w));
        int b = (int)(pr / BIN_W); b = b < 0 ? 0 : (b > NUM_BINS - 1 ? NUM_BINS - 1 : b);
        o.w = s_f[b];
    }
    out[i] = o;
}

extern "C" void kernel_launch(void* const* d_in, const int* in_sizes, int n_in,
                              void* d_out, int out_size, void* d_ws, size_t ws_size,
                              hipStream_t stream) {
    const float* imgs  = (const float*)d_in[0];  // [1,32,3,512,512]
    const float* labs  = (const float*)d_in[1];  // [1,32,1,512,512]
    const float* tlog  = (const float*)d_in[2];  // [1,1,512,512]
    const float* w_img = (const float*)d_in[3];  // [1,3,3,3]
    const float* w_lab = (const float*)d_in[4];  // [1,1,3,3]
    float* out = (float*)d_out;

    float* sumLab = (float*)d_ws;                                       // HW floats
    unsigned int* hist = (unsigned int*)((char*)d_ws + (size_t)HW * sizeof(float));

    k_sumlab<<<HW / 4 / 256, 256, 0, stream>>>((const float4*)labs, (float4*)sumLab, hist);

    k_main<<<UNITS / 4, 256, 0, stream>>>(imgs, labs, sumLab, w_img, w_lab, hist);

    k_out<<<HW / 4 / 256, 256, 0, stream>>>((const float4*)tlog, hist, (float4*)out);
}